// Round 1
// baseline (215.099 us; speedup 1.0000x reference)
//
#include <hip/hip_runtime.h>
#include <math.h>

// Problem constants (fixed by setup_inputs: B=8,T=4096,D=1024,A=32,S=16,ttl=64)
constexpr int kB = 8;
constexpr int kT = 4096;
constexpr int kD = 1024;
constexpr int kA = 32;
constexpr int kS = 16;
constexpr int kH = 256;            // max(ttl*4, S*4)
constexpr int kW = kH - kS + 1;    // 241
constexpr int NC = kD / 256;       // 4 chunks of 256 floats per row (64 lanes x float4)

// --- split Phase-A config ---
constexpr int SPLIT = 8;               // slices per anchor
constexpr int RPS   = kH / SPLIT;      // 32 rows per slice
constexpr int NT1   = 256;             // phase-A block (4 waves)
constexpr int NW1   = NT1 / 64;
constexpr int NWG1  = kB * kA * SPLIT; // 2048 blocks
constexpr int NT2   = 256;             // phase-B block (4 waves)
constexpr int NW2   = NT2 / 64;

// --- fallback single-kernel config ---
constexpr int NTF = 512;
constexpr int NWF = NTF / 64;

__device__ inline float wredsum(float v) {
#pragma unroll
    for (int m = 32; m >= 1; m >>= 1) v += __shfl_xor(v, m, 64);
    return v;
}
__device__ inline float wredmax(float v) {
#pragma unroll
    for (int m = 32; m >= 1; m >>= 1) v = fmaxf(v, __shfl_xor(v, m, 64));
    return v;
}

__device__ inline int alias_of(int t) {
    switch (t) {
        case 11: case 13: case 16: return 11;
        case 21: case 22: case 23: return 21;
        case 31: case 32: case 33: return 31;
        case 41: case 42: case 43: case 44: return 41;
        case 51: case 52: case 53: return 51;
        default: return -1;
    }
}

// ---------------------------------------------------------------------------
// Kernel 1: streaming reduction over the future window, split 8 ways per
// anchor. 2048 blocks x 256 threads -> >=4 blocks/CU for latency hiding.
// Emits per-slice partial dim-sums (1024 f32) and partial shift sums.
// ---------------------------------------------------------------------------
__global__ __launch_bounds__(NT1, 4) void phaseA_kernel(
    const float* __restrict__ hidden,        // (B,T,D)
    const float* __restrict__ anchor_repr,   // (B,A,D)
    const int*   __restrict__ anchor_end,    // (B,A)
    float*       __restrict__ partial,       // [B*A*SPLIT][kD]
    float*       __restrict__ pshift)        // [B*A*SPLIT]
{
    __shared__ float smean[NW1][kD];   // 16 KB
    __shared__ float swshift[NW1];

    // bijective XCD swizzle (NWG1 % 8 == 0): each XCD gets one batch's anchors
    const int id = blockIdx.x;
    const int lb = (id & 7) * (NWG1 / 8) + (id >> 3);   // logical block id
    const int ba    = lb / SPLIT;
    const int slice = lb % SPLIT;
    const int b     = ba / kA;
    const int tid  = threadIdx.x;
    const int lane = tid & 63;
    const int wave = tid >> 6;

    const int e     = anchor_end[ba];
    const int start = e + 1;

    const float* arow = anchor_repr + (size_t)ba * kD;
    float4 anc[NC];
#pragma unroll
    for (int c = 0; c < NC; ++c) anc[c] = *(const float4*)(arow + 256 * c + 4 * lane);

    const float* hbase =
        hidden + ((size_t)b * kT + start + slice * RPS) * kD + 4 * lane;

    float sum[NC][4];
#pragma unroll
    for (int c = 0; c < NC; ++c)
#pragma unroll
        for (int j = 0; j < 4; ++j) sum[c][j] = 0.f;

    float shift_acc = 0.f;
    // wave w owns rows {w, w+4, ..., w+28} of this 32-row slice; 2 rows/iter
    for (int hh = 0; hh < RPS; hh += 2 * NW1) {
        const float* r0 = hbase + (size_t)(hh + wave) * kD;
        const float* r1 = hbase + (size_t)(hh + wave + NW1) * kD;
        float ss0 = 0.f, ss1 = 0.f;
#pragma unroll
        for (int c = 0; c < NC; ++c) {
            float4 x0 = *(const float4*)(r0 + 256 * c);
            float4 x1 = *(const float4*)(r1 + 256 * c);
            float4 a  = anc[c];
            sum[c][0] += x0.x + x1.x;
            sum[c][1] += x0.y + x1.y;
            sum[c][2] += x0.z + x1.z;
            sum[c][3] += x0.w + x1.w;
            float d0 = x0.x - a.x, d1 = x0.y - a.y, d2 = x0.z - a.z, d3 = x0.w - a.w;
            float g0 = x1.x - a.x, g1 = x1.y - a.y, g2 = x1.z - a.z, g3 = x1.w - a.w;
            ss0 += d0*d0 + d1*d1 + d2*d2 + d3*d3;
            ss1 += g0*g0 + g1*g1 + g2*g2 + g3*g3;
        }
        ss0 = wredsum(ss0);
        ss1 = wredsum(ss1);
        shift_acc += sqrtf(ss0) + sqrtf(ss1);   // identical on all lanes
    }
#pragma unroll
    for (int c = 0; c < NC; ++c)
        *(float4*)&smean[wave][256 * c + 4 * lane] =
            make_float4(sum[c][0], sum[c][1], sum[c][2], sum[c][3]);
    if (lane == 0) swshift[wave] = shift_acc;
    __syncthreads();

    // combine 4 wave-partials; thread t owns dims 4t..4t+3 (256*4 = 1024)
    float4 t = make_float4(0.f, 0.f, 0.f, 0.f);
#pragma unroll
    for (int w = 0; w < NW1; ++w) {
        const float4 p = *(const float4*)&smean[w][4 * tid];
        t.x += p.x; t.y += p.y; t.z += p.z; t.w += p.w;
    }
    *(float4*)(partial + ((size_t)lb << 10) + 4 * tid) = t;
    if (tid == 0) {
        float s = 0.f;
#pragma unroll
        for (int w = 0; w < NW1; ++w) s += swshift[w];
        pshift[lb] = s;
    }
}

// ---------------------------------------------------------------------------
// Kernel 2: combine partials (cosine/shift/token stats) + window phase.
// 256 blocks x 256 threads (kW=241 fits in one pass).
// ---------------------------------------------------------------------------
__global__ __launch_bounds__(NT2, 1) void phaseB_kernel(
    const float* __restrict__ anchor_repr,
    const int*   __restrict__ input_ids,
    const int*   __restrict__ anchor_end,
    const float* __restrict__ partial,
    const float* __restrict__ pshift,
    float*       __restrict__ out)
{
    __shared__ int   sfut[kH];
    __shared__ int   sspan[kS];
    __shared__ float sposw[kS];
    __shared__ float sr1[NW2], sr2[NW2], sr3[NW2], sr4[NW2], sr5[NW2];
    __shared__ float s_sim, s_shift, s_hidc, s_tokc;
    __shared__ int   s_root, s_has;
    __shared__ unsigned long long s_spanmask, s_amask, s_hmask;
    __shared__ float s_denom;

    const int ba   = blockIdx.x;
    const int b    = ba / kA;
    const int tid  = threadIdx.x;
    const int lane = tid & 63;
    const int wave = tid >> 6;

    const int e     = anchor_end[ba];
    const int start = e + 1;
    const int* ids  = input_ids + b * kT;
    const int anchor_tok = ids[e];

    sfut[tid] = ids[start + tid];               // NT2 == kH
    if (tid < kS) {
        sspan[tid] = ids[e - kS + 1 + tid];
        sposw[tid] = (1.0f - 0.04f * (float)tid) * (1.0f / 11.2f);
    }

    // ---- combine partial dim-sums: thread t owns dims 4t..4t+3 ----
    const float* arow = anchor_repr + (size_t)ba * kD;
    float4 acc = make_float4(0.f, 0.f, 0.f, 0.f);
#pragma unroll
    for (int s = 0; s < SPLIT; ++s) {
        const float4 p =
            *(const float4*)(partial + (((size_t)ba * SPLIT + s) << 10) + 4 * tid);
        acc.x += p.x; acc.y += p.y; acc.z += p.z; acc.w += p.w;
    }
    const float4 av = *(const float4*)(arow + 4 * tid);
    const float inv_h = 1.0f / (float)kH;
    float mx = acc.x * inv_h, my = acc.y * inv_h, mz = acc.z * inv_h, mw = acc.w * inv_h;
    float pm2  = mx*mx + my*my + mz*mz + mw*mw;
    float pdot = mx*av.x + my*av.y + mz*av.z + mw*av.w;
    float pa2  = av.x*av.x + av.y*av.y + av.z*av.z + av.w*av.w;
    float peq  = (sfut[tid] == anchor_tok) ? 1.f : 0.f;  // own write, no sync needed
    pm2 = wredsum(pm2); pdot = wredsum(pdot); pa2 = wredsum(pa2); peq = wredsum(peq);
    if (lane == 0) { sr1[wave] = pm2; sr2[wave] = pdot; sr3[wave] = pa2; sr4[wave] = peq; }
    __syncthreads();

    if (tid == 0) {
        float m2 = 0.f, dt = 0.f, a2 = 0.f, eqc = 0.f;
        for (int w = 0; w < NW2; ++w) { m2 += sr1[w]; dt += sr2[w]; a2 += sr3[w]; eqc += sr4[w]; }
        float shift = 0.f;
        for (int s = 0; s < SPLIT; ++s) shift += pshift[ba * SPLIT + s];
        float nf = fmaxf(sqrtf(m2), 1e-8f);
        float nr = fmaxf(sqrtf(a2), 1e-8f);
        float sim = dt / (nr * nf);
        s_sim   = sim;
        s_shift = shift * (1.0f / kH);
        s_hidc  = fmaxf(0.f, (1.f - sim) * 0.5f);
        s_tokc  = 1.f - eqc * (1.0f / kH);
    }
    if (tid == 64) {   // span analysis on a different wave than tid==0
        unsigned long long spanmask = 0;
        for (int s = 0; s < kS; ++s) spanmask |= 1ull << sspan[s];
        int root = -1;
        for (int s = 0; s < kS; ++s) { int al = alias_of(sspan[s]); if (al >= 0) { root = al; break; } }
        if (root < 0) {
            int counts[kS], maxc = 0;
            for (int s = 0; s < kS; ++s) {
                int c = 0;
                for (int s2 = 0; s2 < kS; ++s2) c += (sspan[s2] == sspan[s]) ? 1 : 0;
                counts[s] = c; if (c > maxc) maxc = c;
            }
            int mode = 64;
            for (int s = 0; s < kS; ++s) if (counts[s] == maxc && sspan[s] < mode) mode = sspan[s];
            root = mode;
        }
        unsigned long long am = 0, hm = 0; int has = 0;
        switch (root) {  // am: tokens with alias==root; hm: _COMPAT[root] as bitmask
            case 11: am = (1ull<<11)|(1ull<<13)|(1ull<<16);            hm = am;                       has = 1; break;
            case 21: am = (1ull<<21)|(1ull<<22)|(1ull<<23);            hm = am|(1ull<<14)|(1ull<<15); has = 1; break;
            case 31: am = (1ull<<31)|(1ull<<32)|(1ull<<33);            hm = am|(1ull<<15);            has = 1; break;
            case 41: am = (1ull<<41)|(1ull<<42)|(1ull<<43)|(1ull<<44); hm = am;                       has = 1; break;
            case 51: am = (1ull<<51)|(1ull<<52)|(1ull<<53);            hm = am|(1ull<<15);            has = 1; break;
            default: break;
        }
        s_root = root; s_has = has; s_spanmask = spanmask; s_amask = am; s_hmask = hm;
        s_denom = (float)__popcll(spanmask);
    }
    __syncthreads();

    // ---------------- window phase ----------------
    const int root = s_root, has = s_has;
    const unsigned long long spanmask = s_spanmask, amask = s_amask, hmask = s_hmask;
    const float inv_denom = 1.0f / s_denom;

    float sims = -1e30f, rootpers = 0.f, regime = 0.f, simsum = 0.f, cnt = 0.f;
    if (tid < kW) {
        float wex = 0.f, wpos = 0.f, wrp = 0.f, wal = 0.f, whard = 0.f;
        unsigned long long wm = 0;
#pragma unroll
        for (int s = 0; s < kS; ++s) {
            int tok = sfut[tid + s];
            wm |= 1ull << tok;
            bool eq = (tok == sspan[s]);
            wex  += eq ? 1.f : 0.f;
            wpos += eq ? sposw[s] : 0.f;
            wrp  += (tok == root) ? 1.f : 0.f;
            wal  += ((amask >> tok) & 1ull) ? 1.f : 0.f;
            whard += ((hmask >> tok) & 1ull) ? 1.f : 0.f;
        }
        float exact  = wex * (1.f / kS);
        float overlap = (float)__popcll(wm & spanmask) * inv_denom;
        rootpers = wrp * (1.f / kS);
        float aliasc = wal * (1.f / kS);
        float hard   = whard * (1.f / kS);
        regime = has ? (0.55f*hard  + 0.2f*overlap + 0.15f*aliasc + 0.1f*rootpers)
                     : (0.45f*exact + 0.3f*overlap + 0.1f*aliasc  + 0.15f*rootpers);
        sims = 0.25f*exact + 0.15f*overlap + 0.35f*wpos + 0.25f*regime;
        simsum = sims;
        cnt = (sims >= 0.6f) ? 1.f : 0.f;
    }
    float rmax = wredmax(sims);
    float rsum = wredsum(simsum);
    float rrp  = wredsum(rootpers);
    float rreg = wredsum(regime);
    float rcnt = wredsum(cnt);
    if (lane == 0) { sr1[wave] = rmax; sr2[wave] = rsum; sr3[wave] = rrp; sr4[wave] = rreg; sr5[wave] = rcnt; }
    __syncthreads();

    if (tid == 0) {
        float best = -1e30f, ssum = 0.f, srp = 0.f, sreg = 0.f, scnt = 0.f;
        for (int w = 0; w < NW2; ++w) {
            best = fmaxf(best, sr1[w]); ssum += sr2[w]; srp += sr3[w]; sreg += sr4[w]; scnt += sr5[w];
        }
        const float invW = 1.0f / (float)kW;
        float msims = ssum * invW, mrp = srp * invW, mrc = sreg * invW, dmass = scnt * invW;
        float dcoh      = 0.6f*msims + 0.25f*mrp + 0.15f*mrc;
        float pattern_c = 1.f - (0.6f*best + 0.2f*mrp + 0.2f*mrc);
        float contr     = 0.2f*s_hidc + 0.2f*s_tokc + 0.6f*pattern_c;
        contr = fminf(fmaxf(contr, 0.f), 1.f);
        const int n = kB * kA;
        out[0*n + ba] = contr;
        out[1*n + ba] = s_shift;
        out[2*n + ba] = s_sim;
        out[3*n + ba] = s_hidc;
        out[4*n + ba] = s_tokc;
        out[5*n + ba] = pattern_c;
        out[6*n + ba] = dmass;
        out[7*n + ba] = dcoh;
    }
}

// ---------------------------------------------------------------------------
// Fallback: the previous verified single-kernel version (used if workspace
// is too small for the split path).
// ---------------------------------------------------------------------------
__global__ __launch_bounds__(NTF, 1) void monitor_kernel(
    const float* __restrict__ hidden,
    const float* __restrict__ anchor_repr,
    const int*   __restrict__ input_ids,
    const int*   __restrict__ anchor_end,
    float*       __restrict__ out)
{
    __shared__ float smean[NWF][kD];
    __shared__ int   sfut[kH];
    __shared__ int   sspan[kS];
    __shared__ float sposw[kS];
    __shared__ float sr1[NWF], sr2[NWF], sr3[NWF], sr4[NWF], sr5[NWF];
    __shared__ float s_sim, s_shift, s_hidc, s_tokc;
    __shared__ int   s_root, s_has;
    __shared__ unsigned long long s_spanmask, s_amask, s_hmask;
    __shared__ float s_denom;

    const int ba   = blockIdx.x;
    const int b    = ba / kA;
    const int tid  = threadIdx.x;
    const int lane = tid & 63;
    const int wave = tid >> 6;

    const int e     = anchor_end[ba];
    const int start = e + 1;
    const int* ids  = input_ids + b * kT;
    const int anchor_tok = ids[e];

    if (tid < kH) sfut[tid] = ids[start + tid];
    if (tid < kS) {
        sspan[tid] = ids[e - kS + 1 + tid];
        sposw[tid] = (1.0f - 0.04f * (float)tid) * (1.0f / 11.2f);
    }

    const float* arow = anchor_repr + (size_t)ba * kD;
    float4 anc[NC];
#pragma unroll
    for (int c = 0; c < NC; ++c) anc[c] = *(const float4*)(arow + 256 * c + 4 * lane);
    const float* hbase = hidden + ((size_t)b * kT + start) * kD + 4 * lane;

    float sum[NC][4];
#pragma unroll
    for (int c = 0; c < NC; ++c)
#pragma unroll
        for (int j = 0; j < 4; ++j) sum[c][j] = 0.f;

    float shift_acc = 0.f;
    for (int h = wave; h < kH; h += 2 * NWF) {
        const float* r0 = hbase + (size_t)h * kD;
        const float* r1 = hbase + (size_t)(h + NWF) * kD;
        float ss0 = 0.f, ss1 = 0.f;
#pragma unroll
        for (int c = 0; c < NC; ++c) {
            float4 x0 = *(const float4*)(r0 + 256 * c);
            float4 x1 = *(const float4*)(r1 + 256 * c);
            float4 a  = anc[c];
            sum[c][0] += x0.x + x1.x;
            sum[c][1] += x0.y + x1.y;
            sum[c][2] += x0.z + x1.z;
            sum[c][3] += x0.w + x1.w;
            float d0 = x0.x - a.x, d1 = x0.y - a.y, d2 = x0.z - a.z, d3 = x0.w - a.w;
            float g0 = x1.x - a.x, g1 = x1.y - a.y, g2 = x1.z - a.z, g3 = x1.w - a.w;
            ss0 += d0*d0 + d1*d1 + d2*d2 + d3*d3;
            ss1 += g0*g0 + g1*g1 + g2*g2 + g3*g3;
        }
        ss0 = wredsum(ss0);
        ss1 = wredsum(ss1);
        shift_acc += sqrtf(ss0) + sqrtf(ss1);
    }
#pragma unroll
    for (int c = 0; c < NC; ++c)
#pragma unroll
        for (int j = 0; j < 4; ++j) smean[wave][256 * c + 4 * lane + j] = sum[c][j];
    if (lane == 0) sr1[wave] = shift_acc;
    __syncthreads();

    float pm2 = 0.f, pdot = 0.f, pa2 = 0.f;
#pragma unroll
    for (int j = 0; j < kD / NTF; ++j) {
        int d = tid * (kD / NTF) + j;
        float tot = 0.f;
#pragma unroll
        for (int w2 = 0; w2 < NWF; ++w2) tot += smean[w2][d];
        float m  = tot * (1.0f / kH);
        float av = arow[d];
        pm2 += m * m; pdot += m * av; pa2 += av * av;
    }
    float peq = (tid < kH && sfut[tid] == anchor_tok) ? 1.f : 0.f;
    pm2 = wredsum(pm2); pdot = wredsum(pdot); pa2 = wredsum(pa2); peq = wredsum(peq);
    if (lane == 0) { sr2[wave] = pm2; sr3[wave] = pdot; sr4[wave] = pa2; sr5[wave] = peq; }
    __syncthreads();

    if (tid == 0) {
        float shift = 0.f, m2 = 0.f, dt = 0.f, a2 = 0.f, eqc = 0.f;
        for (int w2 = 0; w2 < NWF; ++w2) {
            shift += sr1[w2]; m2 += sr2[w2]; dt += sr3[w2]; a2 += sr4[w2]; eqc += sr5[w2];
        }
        float nf = fmaxf(sqrtf(m2), 1e-8f);
        float nr = fmaxf(sqrtf(a2), 1e-8f);
        float sim = dt / (nr * nf);
        s_sim   = sim;
        s_shift = shift * (1.0f / kH);
        s_hidc  = fmaxf(0.f, (1.f - sim) * 0.5f);
        s_tokc  = 1.f - eqc * (1.0f / kH);
    }
    if (tid == 64) {
        unsigned long long spanmask = 0;
        for (int s = 0; s < kS; ++s) spanmask |= 1ull << sspan[s];
        int root = -1;
        for (int s = 0; s < kS; ++s) { int al = alias_of(sspan[s]); if (al >= 0) { root = al; break; } }
        if (root < 0) {
            int counts[kS], maxc = 0;
            for (int s = 0; s < kS; ++s) {
                int c = 0;
                for (int s2 = 0; s2 < kS; ++s2) c += (sspan[s2] == sspan[s]) ? 1 : 0;
                counts[s] = c; if (c > maxc) maxc = c;
            }
            int mode = 64;
            for (int s = 0; s < kS; ++s) if (counts[s] == maxc && sspan[s] < mode) mode = sspan[s];
            root = mode;
        }
        unsigned long long am = 0, hm = 0; int has = 0;
        switch (root) {
            case 11: am = (1ull<<11)|(1ull<<13)|(1ull<<16);            hm = am;                       has = 1; break;
            case 21: am = (1ull<<21)|(1ull<<22)|(1ull<<23);            hm = am|(1ull<<14)|(1ull<<15); has = 1; break;
            case 31: am = (1ull<<31)|(1ull<<32)|(1ull<<33);            hm = am|(1ull<<15);            has = 1; break;
            case 41: am = (1ull<<41)|(1ull<<42)|(1ull<<43)|(1ull<<44); hm = am;                       has = 1; break;
            case 51: am = (1ull<<51)|(1ull<<52)|(1ull<<53);            hm = am|(1ull<<15);            has = 1; break;
            default: break;
        }
        s_root = root; s_has = has; s_spanmask = spanmask; s_amask = am; s_hmask = hm;
        s_denom = (float)__popcll(spanmask);
    }
    __syncthreads();

    const int root = s_root, has = s_has;
    const unsigned long long spanmask = s_spanmask, amask = s_amask, hmask = s_hmask;
    const float inv_denom = 1.0f / s_denom;

    float sims = -1e30f, rootpers = 0.f, regime = 0.f, simsum = 0.f, cnt = 0.f;
    if (tid < kW) {
        float wex = 0.f, wpos = 0.f, wrp = 0.f, wal = 0.f, whard = 0.f;
        unsigned long long wm = 0;
#pragma unroll
        for (int s = 0; s < kS; ++s) {
            int tok = sfut[tid + s];
            wm |= 1ull << tok;
            bool eq = (tok == sspan[s]);
            wex  += eq ? 1.f : 0.f;
            wpos += eq ? sposw[s] : 0.f;
            wrp  += (tok == root) ? 1.f : 0.f;
            wal  += ((amask >> tok) & 1ull) ? 1.f : 0.f;
            whard += ((hmask >> tok) & 1ull) ? 1.f : 0.f;
        }
        float exact  = wex * (1.f / kS);
        float overlap = (float)__popcll(wm & spanmask) * inv_denom;
        rootpers = wrp * (1.f / kS);
        float aliasc = wal * (1.f / kS);
        float hard   = whard * (1.f / kS);
        regime = has ? (0.55f*hard  + 0.2f*overlap + 0.15f*aliasc + 0.1f*rootpers)
                     : (0.45f*exact + 0.3f*overlap + 0.1f*aliasc  + 0.15f*rootpers);
        sims = 0.25f*exact + 0.15f*overlap + 0.35f*wpos + 0.25f*regime;
        simsum = sims;
        cnt = (sims >= 0.6f) ? 1.f : 0.f;
    }
    float rmax = wredmax(sims);
    float rsum = wredsum(simsum);
    float rrp  = wredsum(rootpers);
    float rreg = wredsum(regime);
    float rcnt = wredsum(cnt);
    if (lane == 0) { sr1[wave] = rmax; sr2[wave] = rsum; sr3[wave] = rrp; sr4[wave] = rreg; sr5[wave] = rcnt; }
    __syncthreads();

    if (tid == 0) {
        float best = -1e30f, ssum = 0.f, srp = 0.f, sreg = 0.f, scnt = 0.f;
        for (int w2 = 0; w2 < NWF; ++w2) {
            best = fmaxf(best, sr1[w2]); ssum += sr2[w2]; srp += sr3[w2]; sreg += sr4[w2]; scnt += sr5[w2];
        }
        const float invW = 1.0f / (float)kW;
        float msims = ssum * invW, mrp = srp * invW, mrc = sreg * invW, dmass = scnt * invW;
        float dcoh      = 0.6f*msims + 0.25f*mrp + 0.15f*mrc;
        float pattern_c = 1.f - (0.6f*best + 0.2f*mrp + 0.2f*mrc);
        float contr     = 0.2f*s_hidc + 0.2f*s_tokc + 0.6f*pattern_c;
        contr = fminf(fmaxf(contr, 0.f), 1.f);
        const int n = kB * kA;
        out[0*n + ba] = contr;
        out[1*n + ba] = s_shift;
        out[2*n + ba] = s_sim;
        out[3*n + ba] = s_hidc;
        out[4*n + ba] = s_tokc;
        out[5*n + ba] = pattern_c;
        out[6*n + ba] = dmass;
        out[7*n + ba] = dcoh;
    }
}

extern "C" void kernel_launch(void* const* d_in, const int* in_sizes, int n_in,
                              void* d_out, int out_size, void* d_ws, size_t ws_size,
                              hipStream_t stream) {
    const float* hidden      = (const float*)d_in[0];
    const float* anchor_repr = (const float*)d_in[1];
    const int*   input_ids   = (const int*)d_in[2];
    const int*   anchor_end  = (const int*)d_in[3];
    float* out = (float*)d_out;

    const size_t n_partial = (size_t)NWG1 * kD;                  // 2M floats (8 MB)
    const size_t need      = (n_partial + NWG1) * sizeof(float); // + 8 KB

    if (d_ws != nullptr && ws_size >= need) {
        float* partial = (float*)d_ws;
        float* pshift  = partial + n_partial;
        hipLaunchKernelGGL(phaseA_kernel, dim3(NWG1), dim3(NT1), 0, stream,
                           hidden, anchor_repr, anchor_end, partial, pshift);
        hipLaunchKernelGGL(phaseB_kernel, dim3(kB * kA), dim3(NT2), 0, stream,
                           anchor_repr, input_ids, anchor_end, partial, pshift, out);
    } else {
        hipLaunchKernelGGL(monitor_kernel, dim3(kB * kA), dim3(NTF), 0, stream,
                           hidden, anchor_repr, input_ids, anchor_end, out);
    }
}

// Round 2
// 212.557 us; speedup vs baseline: 1.0120x; 1.0120x over previous
//
#include <hip/hip_runtime.h>
#include <math.h>

// Problem constants (fixed by setup_inputs: B=8,T=4096,D=1024,A=32,S=16,ttl=64)
constexpr int kB = 8;
constexpr int kT = 4096;
constexpr int kD = 1024;
constexpr int kA = 32;
constexpr int kS = 16;
constexpr int kH = 256;            // max(ttl*4, S*4)
constexpr int kW = kH - kS + 1;    // 241
constexpr int NC = kD / 256;       // 4 chunks of 256 floats per row (64 lanes x float4)

constexpr int NT = 1024;           // 16 waves: 4 waves/SIMD at 1 block/CU
constexpr int NW = NT / 64;        // 16
constexpr int RPW = kH / NW;       // 16 rows per wave
constexpr int GRP = 4;             // rows per reduction group (ILP-4 shfl chains)

__device__ inline float wredsum(float v) {
#pragma unroll
    for (int m = 32; m >= 1; m >>= 1) v += __shfl_xor(v, m, 64);
    return v;
}
__device__ inline float wredmax(float v) {
#pragma unroll
    for (int m = 32; m >= 1; m >>= 1) v = fmaxf(v, __shfl_xor(v, m, 64));
    return v;
}

// _ALIAS table as a switch (tokens are < 64)
__device__ inline int alias_of(int t) {
    switch (t) {
        case 11: case 13: case 16: return 11;
        case 21: case 22: case 23: return 21;
        case 31: case 32: case 33: return 31;
        case 41: case 42: case 43: case 44: return 41;
        case 51: case 52: case 53: return 51;
        default: return -1;
    }
}

__global__ __launch_bounds__(NT) void monitor_kernel(
    const float* __restrict__ hidden,        // (B,T,D) f32
    const float* __restrict__ anchor_repr,   // (B,A,D) f32
    const int*   __restrict__ input_ids,     // (B,T) i32
    const int*   __restrict__ anchor_end,    // (B,A) i32
    float*       __restrict__ out)           // (8,B,A) f32
{
    __shared__ float smean[NW][kD];   // 64 KB per-wave partial dim-sums
    __shared__ int   sfut[kH];
    __shared__ int   sspan[kS];
    __shared__ float sposw[kS];
    __shared__ float sr1[NW], sr2[NW], sr3[NW], sr4[NW], sr5[NW];
    __shared__ float s_sim, s_shift, s_hidc, s_tokc;
    __shared__ int   s_root, s_has;
    __shared__ unsigned long long s_spanmask, s_amask, s_hmask;
    __shared__ float s_denom;

    // XCD swizzle (grid=256, 8 XCDs, bijective): XCD x gets the 32 anchors of
    // batch x -> overlapping future windows share one L2.
    const int id = blockIdx.x;
    const int ba = (id & 7) * 32 + (id >> 3);
    const int b  = ba / kA;

    const int tid  = threadIdx.x;
    const int lane = tid & 63;
    const int wave = tid >> 6;

    const int e     = anchor_end[ba];
    const int start = e + 1;
    const int* ids  = input_ids + b * kT;
    const int anchor_tok = ids[e];

    if (tid < kH) sfut[tid] = ids[start + tid];
    if (tid < kS) {
        sspan[tid] = ids[e - kS + 1 + tid];
        // pos_w = linspace(1.0,0.4,16)/sum; sum = 11.2
        sposw[tid] = (1.0f - 0.04f * (float)tid) * (1.0f / 11.2f);
    }

    // ---------------- Phase A: hidden stats ----------------
    // Wave w owns rows {w, w+16, ..., w+240}. Lane l covers dims c*256+4l..+3.
    // Rows are processed in groups of 4 with NO cross-lane ops inside the
    // group; the 4 shuffle-reduction chains then run with ILP=4.
    const float* arow = anchor_repr + (size_t)ba * kD;
    float4 anc[NC];
#pragma unroll
    for (int c = 0; c < NC; ++c) anc[c] = *(const float4*)(arow + 256 * c + 4 * lane);
    const float* hbase = hidden + ((size_t)b * kT + start) * kD + 4 * lane;

    float sum[NC][4];
#pragma unroll
    for (int c = 0; c < NC; ++c)
#pragma unroll
        for (int j = 0; j < 4; ++j) sum[c][j] = 0.f;

    float shift_acc = 0.f;
    for (int g = 0; g < RPW / GRP; ++g) {
        float ss[GRP];
#pragma unroll
        for (int k = 0; k < GRP; ++k) ss[k] = 0.f;
#pragma unroll
        for (int k = 0; k < GRP; ++k) {
            const float* rp = hbase + (size_t)(wave + NW * (g * GRP + k)) * kD;
#pragma unroll
            for (int c = 0; c < NC; ++c) {
                float4 x = *(const float4*)(rp + 256 * c);
                float4 a = anc[c];
                sum[c][0] += x.x; sum[c][1] += x.y; sum[c][2] += x.z; sum[c][3] += x.w;
                float d0 = x.x - a.x, d1 = x.y - a.y, d2 = x.z - a.z, d3 = x.w - a.w;
                ss[k] += d0*d0 + d1*d1 + d2*d2 + d3*d3;
            }
        }
        // 4 independent 6-step butterfly reductions (ILP hides shfl latency)
#pragma unroll
        for (int m = 32; m >= 1; m >>= 1) {
#pragma unroll
            for (int k = 0; k < GRP; ++k) ss[k] += __shfl_xor(ss[k], m, 64);
        }
#pragma unroll
        for (int k = 0; k < GRP; ++k) shift_acc += sqrtf(ss[k]);
    }
#pragma unroll
    for (int c = 0; c < NC; ++c)
        *(float4*)&smean[wave][256 * c + 4 * lane] =
            make_float4(sum[c][0], sum[c][1], sum[c][2], sum[c][3]);
    if (lane == 0) sr1[wave] = shift_acc;   // identical on all lanes post-reduce
    __syncthreads();

    // combine per-wave dim sums; thread t owns dim t (NT == kD)
    float tot = 0.f;
#pragma unroll
    for (int w = 0; w < NW; ++w) tot += smean[w][tid];
    float m  = tot * (1.0f / kH);
    float av = arow[tid];
    float pm2  = m * m;
    float pdot = m * av;
    float pa2  = av * av;
    float peq  = (tid < kH && sfut[tid] == anchor_tok) ? 1.f : 0.f;
    pm2 = wredsum(pm2); pdot = wredsum(pdot); pa2 = wredsum(pa2); peq = wredsum(peq);
    if (lane == 0) { sr2[wave] = pm2; sr3[wave] = pdot; sr4[wave] = pa2; sr5[wave] = peq; }
    __syncthreads();

    if (tid == 0) {
        float shift = 0.f, m2 = 0.f, dt = 0.f, a2 = 0.f, eqc = 0.f;
        for (int w = 0; w < NW; ++w) {
            shift += sr1[w]; m2 += sr2[w]; dt += sr3[w]; a2 += sr4[w]; eqc += sr5[w];
        }
        float nf = fmaxf(sqrtf(m2), 1e-8f);
        float nr = fmaxf(sqrtf(a2), 1e-8f);
        float sim = dt / (nr * nf);
        s_sim   = sim;
        s_shift = shift * (1.0f / kH);
        s_hidc  = fmaxf(0.f, (1.f - sim) * 0.5f);
        s_tokc  = 1.f - eqc * (1.0f / kH);
    }
    if (tid == 64) {   // span analysis on a different wave than tid==0
        unsigned long long spanmask = 0;
        for (int s = 0; s < kS; ++s) spanmask |= 1ull << sspan[s];
        int root = -1;
        for (int s = 0; s < kS; ++s) { int al = alias_of(sspan[s]); if (al >= 0) { root = al; break; } }
        if (root < 0) {
            int counts[kS], maxc = 0;
            for (int s = 0; s < kS; ++s) {
                int c = 0;
                for (int s2 = 0; s2 < kS; ++s2) c += (sspan[s2] == sspan[s]) ? 1 : 0;
                counts[s] = c; if (c > maxc) maxc = c;
            }
            int mode = 64;
            for (int s = 0; s < kS; ++s) if (counts[s] == maxc && sspan[s] < mode) mode = sspan[s];
            root = mode;
        }
        unsigned long long am = 0, hm = 0; int has = 0;
        switch (root) {  // am: tokens with alias==root; hm: _COMPAT[root] as bitmask
            case 11: am = (1ull<<11)|(1ull<<13)|(1ull<<16);            hm = am;                       has = 1; break;
            case 21: am = (1ull<<21)|(1ull<<22)|(1ull<<23);            hm = am|(1ull<<14)|(1ull<<15); has = 1; break;
            case 31: am = (1ull<<31)|(1ull<<32)|(1ull<<33);            hm = am|(1ull<<15);            has = 1; break;
            case 41: am = (1ull<<41)|(1ull<<42)|(1ull<<43)|(1ull<<44); hm = am;                       has = 1; break;
            case 51: am = (1ull<<51)|(1ull<<52)|(1ull<<53);            hm = am|(1ull<<15);            has = 1; break;
            default: break;
        }
        s_root = root; s_has = has; s_spanmask = spanmask; s_amask = am; s_hmask = hm;
        s_denom = (float)__popcll(spanmask);   // == first_f.sum()
    }
    __syncthreads();

    // ---------------- Phase B: windows ----------------
    const int root = s_root, has = s_has;
    const unsigned long long spanmask = s_spanmask, amask = s_amask, hmask = s_hmask;
    const float inv_denom = 1.0f / s_denom;

    float sims = -1e30f, rootpers = 0.f, regime = 0.f, simsum = 0.f, cnt = 0.f;
    if (tid < kW) {
        float wex = 0.f, wpos = 0.f, wrp = 0.f, wal = 0.f, whard = 0.f;
        unsigned long long wm = 0;
#pragma unroll
        for (int s = 0; s < kS; ++s) {
            int tok = sfut[tid + s];
            wm |= 1ull << tok;
            bool eq = (tok == sspan[s]);
            wex  += eq ? 1.f : 0.f;
            wpos += eq ? sposw[s] : 0.f;
            wrp  += (tok == root) ? 1.f : 0.f;
            wal  += ((amask >> tok) & 1ull) ? 1.f : 0.f;
            whard += ((hmask >> tok) & 1ull) ? 1.f : 0.f;
        }
        float exact  = wex * (1.f / kS);
        // overlap = |distinct(span) ∩ window| / |distinct(span)|
        float overlap = (float)__popcll(wm & spanmask) * inv_denom;
        rootpers = wrp * (1.f / kS);
        float aliasc = wal * (1.f / kS);
        float hard   = whard * (1.f / kS);
        regime = has ? (0.55f*hard  + 0.2f*overlap + 0.15f*aliasc + 0.1f*rootpers)
                     : (0.45f*exact + 0.3f*overlap + 0.1f*aliasc  + 0.15f*rootpers);
        sims = 0.25f*exact + 0.15f*overlap + 0.35f*wpos + 0.25f*regime;
        simsum = sims;
        cnt = (sims >= 0.6f) ? 1.f : 0.f;
    }
    float rmax = wredmax(sims);
    float rsum = wredsum(simsum);
    float rrp  = wredsum(rootpers);
    float rreg = wredsum(regime);
    float rcnt = wredsum(cnt);
    if (lane == 0) { sr1[wave] = rmax; sr2[wave] = rsum; sr3[wave] = rrp; sr4[wave] = rreg; sr5[wave] = rcnt; }
    __syncthreads();

    if (tid == 0) {
        float best = -1e30f, ssum = 0.f, srp = 0.f, sreg = 0.f, scnt = 0.f;
        for (int w = 0; w < NW; ++w) {
            best = fmaxf(best, sr1[w]); ssum += sr2[w]; srp += sr3[w]; sreg += sr4[w]; scnt += sr5[w];
        }
        const float invW = 1.0f / (float)kW;
        float msims = ssum * invW, mrp = srp * invW, mrc = sreg * invW, dmass = scnt * invW;
        float dcoh      = 0.6f*msims + 0.25f*mrp + 0.15f*mrc;
        float pattern_c = 1.f - (0.6f*best + 0.2f*mrp + 0.2f*mrc);
        float contr     = 0.2f*s_hidc + 0.2f*s_tokc + 0.6f*pattern_c;
        contr = fminf(fmaxf(contr, 0.f), 1.f);
        const int n = kB * kA;
        out[0*n + ba] = contr;
        out[1*n + ba] = s_shift;
        out[2*n + ba] = s_sim;
        out[3*n + ba] = s_hidc;
        out[4*n + ba] = s_tokc;
        out[5*n + ba] = pattern_c;
        out[6*n + ba] = dmass;
        out[7*n + ba] = dcoh;
    }
}

extern "C" void kernel_launch(void* const* d_in, const int* in_sizes, int n_in,
                              void* d_out, int out_size, void* d_ws, size_t ws_size,
                              hipStream_t stream) {
    const float* hidden      = (const float*)d_in[0];
    const float* anchor_repr = (const float*)d_in[1];
    const int*   input_ids   = (const int*)d_in[2];
    const int*   anchor_end  = (const int*)d_in[3];
    // d_in[4]=span_len(16), d_in[5]=ttl(64) — compile-time constants here
    float* out = (float*)d_out;
    (void)d_ws; (void)ws_size;   // deliberately unused: ws use drags a 536 MB
                                 // re-poison fill into every iteration

    hipLaunchKernelGGL(monitor_kernel, dim3(kB * kA), dim3(NT), 0, stream,
                       hidden, anchor_repr, input_ids, anchor_end, out);
}